// Round 3
// baseline (644.553 us; speedup 1.0000x reference)
//
#include <hip/hip_runtime.h>
#include <hip/hip_bf16.h>

// Tree-LSTM, depth-15 complete binary tree. N=32767, state 2H=512, gates 2048.
// R3: GEMM+LSTM fused (no gates materialization).
//  - W_hh pre-swizzled to MFMA B-fragment bf16 hi/lo tables (split -> ~fp32 accuracy)
//  - block = M nodes (A hi/lo in LDS, full K=512), waves own 16-col j-steps,
//    accumulate 4 gate-quadrant tiles, apply LSTM in-register, write h/c directly.

#define NNODES 32767

typedef __attribute__((ext_vector_type(8))) short bf16x8;
typedef __attribute__((ext_vector_type(4))) float f32x4;

__device__ __forceinline__ float sigf(float x) { return 1.0f / (1.0f + __expf(-x)); }
__device__ __forceinline__ float tanhfast(float x) { return 2.0f / (1.0f + __expf(-2.0f * x)) - 1.0f; }

__device__ __forceinline__ short bf_hi(float x) {
    __hip_bfloat16 h = __float2bfloat16(x);
    return __builtin_bit_cast(short, h);
}
__device__ __forceinline__ float bf_f(short s) {
    __hip_bfloat16 h = __builtin_bit_cast(__hip_bfloat16, s);
    return __bfloat162float(h);
}
__device__ __forceinline__ void split8(const float* src, short* hi, short* lo) {
#pragma unroll
    for (int j = 0; j < 8; ++j) {
        float x = src[j];
        short h = bf_hi(x);
        hi[j] = h;
        lo[j] = bf_hi(x - bf_f(h));
    }
}

// proj[v][r] = dot(emb[v], W_ih[r]) + b_ih[r] + b_hh[r];  grid 256, block 256
__global__ void proj_kernel(const float* __restrict__ emb, const float* __restrict__ W_ih,
                            const float* __restrict__ b_ih, const float* __restrict__ b_hh,
                            float* __restrict__ proj) {
    __shared__ float e[256];
    int v = blockIdx.x >> 3;
    int rc = blockIdx.x & 7;
    int t = threadIdx.x;
    e[t] = emb[v * 256 + t];
    __syncthreads();
    int r = rc * 256 + t;
    const float4* w4 = (const float4*)(W_ih + (size_t)r * 256);
    const float4* e4 = (const float4*)e;
    float acc = 0.f;
#pragma unroll 8
    for (int k = 0; k < 64; ++k) {
        float4 w = w4[k];
        float4 h = e4[k];
        acc += w.x * h.x + w.y * h.y + w.z * h.z + w.w * h.w;
    }
    proj[v * 2048 + r] = acc + b_ih[r] + b_hh[r];
}

// W_hh [2048][512] fp32 -> MFMA B-fragment bf16 hi/lo tables.
// frag addr (shorts): ((ntile*16 + kt)*64 + lane)*8 ; lane holds n=ntile*16+(lane&15),
// k = kt*32 + (lane>>4)*8 + j.  grid 512, block 256.
__global__ void wpack_kernel(const float* __restrict__ W_hh,
                             short* __restrict__ Whi, short* __restrict__ Wlo) {
    int t = blockIdx.x * 256 + threadIdx.x;
    int lane = t & 63;
    int kt = (t >> 6) & 15;
    int ntile = t >> 10;
    int n = ntile * 16 + (lane & 15);
    int k0 = kt * 32 + (lane >> 4) * 8;
    const float* src = W_hh + (size_t)n * 512 + k0;
    short hi[8], lo[8];
    split8(src, hi, lo);
    *(bf16x8*)(Whi + (size_t)t * 8) = *(bf16x8*)hi;
    *(bf16x8*)(Wlo + (size_t)t * 8) = *(bf16x8*)lo;
}

// leaves: gates = proj[type]; zero child state.  grid 32768, block 256
__global__ void leaf_kernel(const int* __restrict__ types, const float* __restrict__ proj,
                            float* __restrict__ out, float* __restrict__ C256) {
    int bi = blockIdx.x;
    int node = 16383 + (bi >> 1);
    int j = ((bi & 1) << 8) + threadIdx.x;
    int tt = types[node];
    const float* p = proj + (size_t)tt * 2048;
    float gi = p[j];
    float gg = p[1024 + j];
    float go = p[1536 + j];
    float cn = sigf(gi) * tanhfast(gg);
    float hn = sigf(go) * tanhfast(cn);
    out[(size_t)node * 512 + j] = hn;
    if ((bi & 1) == 0) C256[(size_t)node * 256 + j] = cn;
}

// Fused MFMA GEMM + LSTM. M = MT*16 nodes per block; block y owns Jc j-columns.
// Waves take 16-col j-steps round-robin; per j-step accumulate 4 quadrant tiles
// over K=512, then LSTM epilogue writes h (out) and c (C256, first 256 cols).
template <int MT>
__global__ __launch_bounds__(256) void gemm_lstm_kernel(
    const int* __restrict__ a_idx, const int* __restrict__ b_idx,
    const int* __restrict__ types, float* __restrict__ out,
    const short* __restrict__ Whi, const short* __restrict__ Wlo,
    const float* __restrict__ proj, float* __restrict__ C256,
    int node_base, int Jc) {
    __shared__ short Ahi[MT][16][64][8];
    __shared__ short Alo[MT][16][64][8];
    __shared__ int sA[MT * 16], sB[MT * 16], sT[MT * 16];
    int t = threadIdx.x;
    int node0 = node_base + blockIdx.x * (MT * 16);
    if (t < MT * 16) {
        sA[t] = a_idx[node0 + t];
        sB[t] = b_idx[node0 + t];
        sT[t] = types[node0 + t];
    }
    __syncthreads();

    // gather children h, split to bf16 hi/lo, store in A-fragment layout
#pragma unroll
    for (int it = 0; it < MT * 4; ++it) {
        int c = it * 256 + t;
        int mt = c >> 10;
        int kt = (c >> 6) & 15;
        int lane = c & 63;
        int m_loc = mt * 16 + (lane & 15);
        int k0 = kt * 32 + (lane >> 4) * 8;
        int child = (k0 < 256) ? sA[m_loc] : sB[m_loc];
        const float* src = out + (size_t)child * 512 + (k0 & 255);
        short hi[8], lo[8];
        split8(src, hi, lo);
        *(bf16x8*)&Ahi[mt][kt][lane][0] = *(bf16x8*)hi;
        *(bf16x8*)&Alo[mt][kt][lane][0] = *(bf16x8*)lo;
    }
    __syncthreads();

    int w = t >> 6;
    int lane = t & 63;
    int jsteps = Jc >> 4;
    int jbase = blockIdx.y * Jc;

    for (int js = w; js < jsteps; js += 4) {
        int j0 = jbase + js * 16;
        f32x4 acc[4][MT];
#pragma unroll
        for (int q = 0; q < 4; ++q)
#pragma unroll
            for (int mt = 0; mt < MT; ++mt) acc[q][mt] = (f32x4){0.f, 0.f, 0.f, 0.f};

        int nt0 = j0 >> 4;
        for (int kt = 0; kt < 16; ++kt) {
            bf16x8 ah[MT], al[MT];
#pragma unroll
            for (int mt = 0; mt < MT; ++mt) {
                ah[mt] = *(const bf16x8*)&Ahi[mt][kt][lane][0];
                al[mt] = *(const bf16x8*)&Alo[mt][kt][lane][0];
            }
#pragma unroll
            for (int q = 0; q < 4; ++q) {
                int ntile = q * 32 + nt0;
                size_t off = ((size_t)(ntile * 16 + kt) * 64 + lane) * 8;
                bf16x8 bh = *(const bf16x8*)(Whi + off);
                bf16x8 bl = *(const bf16x8*)(Wlo + off);
#pragma unroll
                for (int mt = 0; mt < MT; ++mt) {
                    acc[q][mt] = __builtin_amdgcn_mfma_f32_16x16x32_bf16(ah[mt], bh, acc[q][mt], 0, 0, 0);
                    acc[q][mt] = __builtin_amdgcn_mfma_f32_16x16x32_bf16(ah[mt], bl, acc[q][mt], 0, 0, 0);
                    acc[q][mt] = __builtin_amdgcn_mfma_f32_16x16x32_bf16(al[mt], bh, acc[q][mt], 0, 0, 0);
                }
            }
        }

        // LSTM epilogue. C/D layout: col = j0+(lane&15), row = (lane>>4)*4 + reg.
        int j = j0 + (lane & 15);
        int jc = j & 255;
        bool firsthalf = (j < 256);
#pragma unroll
        for (int mt = 0; mt < MT; ++mt) {
            int mrow = mt * 16 + (lane >> 4) * 4;
#pragma unroll
            for (int r = 0; r < 4; ++r) {
                int m_loc = mrow + r;
                int node = node0 + m_loc;
                const float* p = proj + (size_t)sT[m_loc] * 2048 + j;
                float gi = acc[0][mt][r] + p[0];
                float gf = acc[1][mt][r] + p[512];
                float gg = acc[2][mt][r] + p[1024];
                float go = acc[3][mt][r] + p[1536];
                int child = firsthalf ? sA[m_loc] : sB[m_loc];
                float c = C256[(size_t)child * 256 + jc];
                float cn = sigf(gf) * c + sigf(gi) * tanhfast(gg);
                float hn = sigf(go) * tanhfast(cn);
                out[(size_t)node * 512 + j] = hn;
                if (firsthalf) C256[(size_t)node * 256 + j] = cn;
            }
        }
    }
}

// small levels (B < 32): fused fp32 matvec + LSTM. grid (B, 2), block 256.
// thread t handles column j = by*256+t: 4 gate rows + LSTM.
__global__ void small_lstm_kernel(
    const int* __restrict__ a_idx, const int* __restrict__ b_idx,
    const int* __restrict__ types, float* __restrict__ out,
    const float* __restrict__ W_hh, const float* __restrict__ proj,
    float* __restrict__ C256, int node_base) {
    __shared__ float hs[512];
    int t = threadIdx.x;
    int node = node_base + blockIdx.x;
    if (t < 128) {
        int child = (t < 64) ? a_idx[node] : b_idx[node];
        float4 v = ((const float4*)(out + (size_t)child * 512))[t & 63];
        ((float4*)hs)[t] = v;
    }
    __syncthreads();
    int j = blockIdx.y * 256 + t;
    const float4* h4 = (const float4*)hs;
    float accq[4];
#pragma unroll
    for (int q = 0; q < 4; ++q) {
        const float4* w4 = (const float4*)(W_hh + (size_t)(q * 512 + j) * 512);
        float acc = 0.f;
#pragma unroll 8
        for (int k = 0; k < 128; ++k) {
            float4 wv = w4[k];
            float4 hv = h4[k];
            acc += wv.x * hv.x + wv.y * hv.y + wv.z * hv.z + wv.w * hv.w;
        }
        accq[q] = acc;
    }
    int tt = types[node];
    const float* p = proj + (size_t)tt * 2048 + j;
    float gi = accq[0] + p[0];
    float gf = accq[1] + p[512];
    float gg = accq[2] + p[1024];
    float go = accq[3] + p[1536];
    int child = (j < 256) ? a_idx[node] : b_idx[node];
    float c = C256[(size_t)child * 256 + (j & 255)];
    float cn = sigf(gf) * c + sigf(gi) * tanhfast(gg);
    float hn = sigf(go) * tanhfast(cn);
    out[(size_t)node * 512 + j] = hn;
    if (j < 256) C256[(size_t)node * 256 + j] = cn;
}

extern "C" void kernel_launch(void* const* d_in, const int* in_sizes, int n_in,
                              void* d_out, int out_size, void* d_ws, size_t ws_size,
                              hipStream_t stream) {
    const int* types = (const int*)d_in[0];
    const int* a_idx = (const int*)d_in[1];
    const int* b_idx = (const int*)d_in[2];
    const float* emb = (const float*)d_in[3];
    const float* W_ih = (const float*)d_in[4];
    const float* W_hh = (const float*)d_in[5];
    const float* b_ih = (const float*)d_in[6];
    const float* b_hh = (const float*)d_in[7];
    float* out = (float*)d_out;

    float* ws = (float*)d_ws;
    float* proj = ws;                          // 32*2048 floats (256 KB)
    float* C256 = ws + 65536;                  // 32767*256 floats (32 MB)
    short* Whi = (short*)(ws + 65536 + 8388352);  // 2 MB
    short* Wlo = Whi + 2048 * 512;                // 2 MB
    // total ws use ~38 MB

    proj_kernel<<<256, 256, 0, stream>>>(emb, W_ih, b_ih, b_hh, proj);
    wpack_kernel<<<512, 256, 0, stream>>>(W_hh, Whi, Wlo);
    leaf_kernel<<<32768, 256, 0, stream>>>(types, proj, out, C256);

    for (int d = 13; d >= 0; --d) {
        int base = (1 << d) - 1;
        int B = 1 << d;
        if (B >= 1024) {
            int J = (B == 8192) ? 2 : (B == 4096) ? 4 : 8;  // blocks = (B/32)*J in [256,512]
            gemm_lstm_kernel<2><<<dim3(B / 32, J), 256, 0, stream>>>(
                a_idx, b_idx, types, out, Whi, Wlo, proj, C256, base, 512 / J);
        } else if (B >= 32) {
            gemm_lstm_kernel<1><<<dim3(B / 16, 8), 256, 0, stream>>>(
                a_idx, b_idx, types, out, Whi, Wlo, proj, C256, base, 64);
        } else {
            small_lstm_kernel<<<dim3(B, 2), 256, 0, stream>>>(
                a_idx, b_idx, types, out, W_hh, proj, C256, base);
        }
    }
}

// Round 4
// 461.858 us; speedup vs baseline: 1.3956x; 1.3956x over previous
//
#include <hip/hip_runtime.h>
#include <hip/hip_bf16.h>

// Tree-LSTM, depth-15 complete binary tree. N=32767, state 2H=512, gates 2048.
// R4: tail-level parallelism + pre-split h (Hsplit) + kt-loop unroll.
//  - Hsplit[node] = 256 hi bf16 ‖ 256 lo bf16 of h[0:256] (what parents consume)
//  - MFMA levels (B>=32): grid (B/32, J), J up to 16; Jc=32 -> wave-pair K-split
//  - B<=16: fp32 K-split gemm (grid B x 8 x 8) + fused combine/LSTM kernel

#define NNODES 32767

typedef __attribute__((ext_vector_type(8))) short bf16x8;
typedef __attribute__((ext_vector_type(4))) float f32x4;

__device__ __forceinline__ float sigf(float x) { return 1.0f / (1.0f + __expf(-x)); }
__device__ __forceinline__ float tanhfast(float x) { return 2.0f / (1.0f + __expf(-2.0f * x)) - 1.0f; }

__device__ __forceinline__ short bf_hi(float x) {
    __hip_bfloat16 h = __float2bfloat16(x);
    return __builtin_bit_cast(short, h);
}
__device__ __forceinline__ float bf_f(short s) {
    __hip_bfloat16 h = __builtin_bit_cast(__hip_bfloat16, s);
    return __bfloat162float(h);
}
__device__ __forceinline__ void split8(const float* src, short* hi, short* lo) {
#pragma unroll
    for (int j = 0; j < 8; ++j) {
        float x = src[j];
        short h = bf_hi(x);
        hi[j] = h;
        lo[j] = bf_hi(x - bf_f(h));
    }
}

// proj[v][r] = dot(emb[v], W_ih[r]) + b_ih[r] + b_hh[r];  grid 256, block 256
__global__ void proj_kernel(const float* __restrict__ emb, const float* __restrict__ W_ih,
                            const float* __restrict__ b_ih, const float* __restrict__ b_hh,
                            float* __restrict__ proj) {
    __shared__ float e[256];
    int v = blockIdx.x >> 3;
    int rc = blockIdx.x & 7;
    int t = threadIdx.x;
    e[t] = emb[v * 256 + t];
    __syncthreads();
    int r = rc * 256 + t;
    const float4* w4 = (const float4*)(W_ih + (size_t)r * 256);
    const float4* e4 = (const float4*)e;
    float acc = 0.f;
#pragma unroll 8
    for (int k = 0; k < 64; ++k) {
        float4 w = w4[k];
        float4 h = e4[k];
        acc += w.x * h.x + w.y * h.y + w.z * h.z + w.w * h.w;
    }
    proj[v * 2048 + r] = acc + b_ih[r] + b_hh[r];
}

// W_hh [2048][512] fp32 -> MFMA B-fragment bf16 hi/lo tables.  grid 512, block 256
__global__ void wpack_kernel(const float* __restrict__ W_hh,
                             short* __restrict__ Whi, short* __restrict__ Wlo) {
    int t = blockIdx.x * 256 + threadIdx.x;
    int lane = t & 63;
    int kt = (t >> 6) & 15;
    int ntile = t >> 10;
    int n = ntile * 16 + (lane & 15);
    int k0 = kt * 32 + (lane >> 4) * 8;
    const float* src = W_hh + (size_t)n * 512 + k0;
    short hi[8], lo[8];
    split8(src, hi, lo);
    *(bf16x8*)(Whi + (size_t)t * 8) = *(bf16x8*)hi;
    *(bf16x8*)(Wlo + (size_t)t * 8) = *(bf16x8*)lo;
}

// leaves: gates = proj[type].  grid 32768, block 256
__global__ void leaf_kernel(const int* __restrict__ types, const float* __restrict__ proj,
                            float* __restrict__ out, float* __restrict__ C256,
                            short* __restrict__ Hsplit) {
    int bi = blockIdx.x;
    int node = 16383 + (bi >> 1);
    int j = ((bi & 1) << 8) + threadIdx.x;
    int tt = types[node];
    const float* p = proj + (size_t)tt * 2048;
    float gi = p[j];
    float gg = p[1024 + j];
    float go = p[1536 + j];
    float cn = sigf(gi) * tanhfast(gg);
    float hn = sigf(go) * tanhfast(cn);
    out[(size_t)node * 512 + j] = hn;
    if ((bi & 1) == 0) {
        C256[(size_t)node * 256 + j] = cn;
        short hi = bf_hi(hn);
        Hsplit[(size_t)node * 512 + j] = hi;
        Hsplit[(size_t)node * 512 + 256 + j] = bf_hi(hn - bf_f(hi));
    }
}

// Fused MFMA GEMM + LSTM.  32 nodes/block, grid (B/32, J), Jc = 512/J.
// jsteps = Jc/16.  jsteps>=4: waves round-robin j-steps.  jsteps==2: wave pairs
// split K in half, partials combined via LDS (reusing the A buffer).
__global__ __launch_bounds__(256) void gemm_lstm_kernel(
    const int* __restrict__ a_idx, const int* __restrict__ b_idx,
    const int* __restrict__ types, float* __restrict__ out,
    const short* __restrict__ Whi, const short* __restrict__ Wlo,
    const float* __restrict__ proj, float* __restrict__ C256,
    short* __restrict__ Hsplit, int node_base, int Jc) {
    __shared__ short Ahi[2][16][64][8];   // 32 KB
    __shared__ short Alo[2][16][64][8];   // 32 KB
    __shared__ int sA[32], sB[32], sT[32];
    int t = threadIdx.x;
    int node0 = node_base + blockIdx.x * 32;
    if (t < 32) {
        sA[t] = a_idx[node0 + t];
        sB[t] = b_idx[node0 + t];
        sT[t] = types[node0 + t];
    }
    __syncthreads();

    // stage A fragments from pre-split Hsplit (pure copies, no VALU)
#pragma unroll
    for (int it = 0; it < 8; ++it) {
        int c = it * 256 + t;
        int mt = c >> 10;
        int kt = (c >> 6) & 15;
        int lane = c & 63;
        int m_loc = mt * 16 + (lane & 15);
        int k0 = kt * 32 + (lane >> 4) * 8;
        int child = (k0 < 256) ? sA[m_loc] : sB[m_loc];
        const short* src = Hsplit + (size_t)child * 512 + (k0 & 255);
        *(bf16x8*)&Ahi[mt][kt][lane][0] = *(const bf16x8*)src;
        *(bf16x8*)&Alo[mt][kt][lane][0] = *(const bf16x8*)(src + 256);
    }
    __syncthreads();

    int w = t >> 6;
    int lane = t & 63;
    int jsteps = Jc >> 4;
    int jbase = blockIdx.y * Jc;

    auto epilogue = [&](int j0, f32x4 (&acc)[4][2]) {
        int j = j0 + (lane & 15);
        int jc = j & 255;
        bool fh = (j < 256);
#pragma unroll
        for (int mt = 0; mt < 2; ++mt) {
            int mrow = mt * 16 + (lane >> 4) * 4;
#pragma unroll
            for (int r = 0; r < 4; ++r) {
                int m_loc = mrow + r;
                int node = node0 + m_loc;
                const float* p = proj + (size_t)sT[m_loc] * 2048 + j;
                float gi = acc[0][mt][r] + p[0];
                float gf = acc[1][mt][r] + p[512];
                float gg = acc[2][mt][r] + p[1024];
                float go = acc[3][mt][r] + p[1536];
                int child = fh ? sA[m_loc] : sB[m_loc];
                float c = C256[(size_t)child * 256 + jc];
                float cn = sigf(gf) * c + sigf(gi) * tanhfast(gg);
                float hn = sigf(go) * tanhfast(cn);
                out[(size_t)node * 512 + j] = hn;
                if (fh) {
                    C256[(size_t)node * 256 + j] = cn;
                    short hi = bf_hi(hn);
                    Hsplit[(size_t)node * 512 + j] = hi;
                    Hsplit[(size_t)node * 512 + 256 + j] = bf_hi(hn - bf_f(hi));
                }
            }
        }
    };

    if (jsteps >= 4) {
        for (int js = w; js < jsteps; js += 4) {
            int j0 = jbase + js * 16;
            f32x4 acc[4][2];
#pragma unroll
            for (int q = 0; q < 4; ++q)
#pragma unroll
                for (int mt = 0; mt < 2; ++mt) acc[q][mt] = (f32x4){0.f, 0.f, 0.f, 0.f};
            int nt0 = j0 >> 4;
#pragma unroll 4
            for (int kt = 0; kt < 16; ++kt) {
                bf16x8 ah0 = *(const bf16x8*)&Ahi[0][kt][lane][0];
                bf16x8 al0 = *(const bf16x8*)&Alo[0][kt][lane][0];
                bf16x8 ah1 = *(const bf16x8*)&Ahi[1][kt][lane][0];
                bf16x8 al1 = *(const bf16x8*)&Alo[1][kt][lane][0];
#pragma unroll
                for (int q = 0; q < 4; ++q) {
                    int ntile = q * 32 + nt0;
                    size_t off = ((size_t)(ntile * 16 + kt) * 64 + lane) * 8;
                    bf16x8 bh = *(const bf16x8*)(Whi + off);
                    bf16x8 bl = *(const bf16x8*)(Wlo + off);
                    acc[q][0] = __builtin_amdgcn_mfma_f32_16x16x32_bf16(ah0, bh, acc[q][0], 0, 0, 0);
                    acc[q][0] = __builtin_amdgcn_mfma_f32_16x16x32_bf16(ah0, bl, acc[q][0], 0, 0, 0);
                    acc[q][0] = __builtin_amdgcn_mfma_f32_16x16x32_bf16(al0, bh, acc[q][0], 0, 0, 0);
                    acc[q][1] = __builtin_amdgcn_mfma_f32_16x16x32_bf16(ah1, bh, acc[q][1], 0, 0, 0);
                    acc[q][1] = __builtin_amdgcn_mfma_f32_16x16x32_bf16(ah1, bl, acc[q][1], 0, 0, 0);
                    acc[q][1] = __builtin_amdgcn_mfma_f32_16x16x32_bf16(al1, bh, acc[q][1], 0, 0, 0);
                }
            }
            epilogue(j0, acc);
        }
    } else {
        // jsteps == 2: wave pairs split K. wave w: js = w&1, khalf = w>>1.
        int js = w & 1;
        int khalf = w >> 1;
        int j0 = jbase + js * 16;
        f32x4 acc[4][2];
#pragma unroll
        for (int q = 0; q < 4; ++q)
#pragma unroll
            for (int mt = 0; mt < 2; ++mt) acc[q][mt] = (f32x4){0.f, 0.f, 0.f, 0.f};
        int nt0 = j0 >> 4;
        int kt0 = khalf * 8;
#pragma unroll 4
        for (int kt = kt0; kt < kt0 + 8; ++kt) {
            bf16x8 ah0 = *(const bf16x8*)&Ahi[0][kt][lane][0];
            bf16x8 al0 = *(const bf16x8*)&Alo[0][kt][lane][0];
            bf16x8 ah1 = *(const bf16x8*)&Ahi[1][kt][lane][0];
            bf16x8 al1 = *(const bf16x8*)&Alo[1][kt][lane][0];
#pragma unroll
            for (int q = 0; q < 4; ++q) {
                int ntile = q * 32 + nt0;
                size_t off = ((size_t)(ntile * 16 + kt) * 64 + lane) * 8;
                bf16x8 bh = *(const bf16x8*)(Whi + off);
                bf16x8 bl = *(const bf16x8*)(Wlo + off);
                acc[q][0] = __builtin_amdgcn_mfma_f32_16x16x32_bf16(ah0, bh, acc[q][0], 0, 0, 0);
                acc[q][0] = __builtin_amdgcn_mfma_f32_16x16x32_bf16(ah0, bl, acc[q][0], 0, 0, 0);
                acc[q][0] = __builtin_amdgcn_mfma_f32_16x16x32_bf16(al0, bh, acc[q][0], 0, 0, 0);
                acc[q][1] = __builtin_amdgcn_mfma_f32_16x16x32_bf16(ah1, bh, acc[q][1], 0, 0, 0);
                acc[q][1] = __builtin_amdgcn_mfma_f32_16x16x32_bf16(ah1, bl, acc[q][1], 0, 0, 0);
                acc[q][1] = __builtin_amdgcn_mfma_f32_16x16x32_bf16(al1, bh, acc[q][1], 0, 0, 0);
            }
        }
        __syncthreads();  // all waves done reading A; reuse Ahi as fp32 exchange
        float* xch = (float*)&Ahi[0][0][0][0];  // 16 KB used
        if (khalf == 1) {
#pragma unroll
            for (int q = 0; q < 4; ++q)
#pragma unroll
                for (int mt = 0; mt < 2; ++mt)
                    *(f32x4*)&xch[(((q * 2 + mt) * 128) + js * 64 + lane) * 4] = acc[q][mt];
        }
        __syncthreads();
        if (khalf == 0) {
#pragma unroll
            for (int q = 0; q < 4; ++q)
#pragma unroll
                for (int mt = 0; mt < 2; ++mt) {
                    f32x4 o = *(const f32x4*)&xch[(((q * 2 + mt) * 128) + js * 64 + lane) * 4];
                    acc[q][mt] += o;
                }
            epilogue(j0, acc);
        }
    }
}

// B<=16 levels: fp32 partial GEMM, grid (B, 8, 8), block 256.
// block (n, y, z): rows y*256..+255, k z*64..+63 -> part[z][n][row]
__global__ void small_gemm_kernel(
    const int* __restrict__ a_idx, const int* __restrict__ b_idx,
    const float* __restrict__ out, const float* __restrict__ W_hh,
    float* __restrict__ part, int node_base) {
    __shared__ float hs[64];
    int t = threadIdx.x;
    int n = blockIdx.x;
    int node = node_base + n;
    int kbase = blockIdx.z * 64;
    if (t < 16) {
        int child = (kbase < 256) ? a_idx[node] : b_idx[node];
        float4 v = ((const float4*)(out + (size_t)child * 512 + (kbase & 255)))[t];
        ((float4*)hs)[t] = v;
    }
    __syncthreads();
    int r = blockIdx.y * 256 + t;
    const float4* w4 = (const float4*)(W_hh + (size_t)r * 512 + kbase);
    const float4* h4 = (const float4*)hs;
    float acc = 0.f;
#pragma unroll
    for (int k = 0; k < 16; ++k) {
        float4 wv = w4[k];
        float4 hv = h4[k];
        acc += wv.x * hv.x + wv.y * hv.y + wv.z * hv.z + wv.w * hv.w;
    }
    part[((size_t)blockIdx.z * gridDim.x + n) * 2048 + r] = acc;
}

// combine K-partials + LSTM.  grid (B*2), block 256
__global__ void small_combine_kernel(
    const int* __restrict__ a_idx, const int* __restrict__ b_idx,
    const int* __restrict__ types, const float* __restrict__ part,
    const float* __restrict__ proj, float* __restrict__ C256,
    short* __restrict__ Hsplit, float* __restrict__ out, int node_base, int B) {
    int bi = blockIdx.x;
    int n = bi >> 1;
    int j = ((bi & 1) << 8) + threadIdx.x;
    int node = node_base + n;
    float g[4] = {0.f, 0.f, 0.f, 0.f};
    for (int z = 0; z < 8; ++z) {
        const float* p = part + ((size_t)z * B + n) * 2048;
#pragma unroll
        for (int q = 0; q < 4; ++q) g[q] += p[q * 512 + j];
    }
    const float* p = proj + (size_t)types[node] * 2048 + j;
    float gi = g[0] + p[0];
    float gf = g[1] + p[512];
    float gg = g[2] + p[1024];
    float go = g[3] + p[1536];
    int child = (j < 256) ? a_idx[node] : b_idx[node];
    float c = C256[(size_t)child * 256 + (j & 255)];
    float cn = sigf(gf) * c + sigf(gi) * tanhfast(gg);
    float hn = sigf(go) * tanhfast(cn);
    out[(size_t)node * 512 + j] = hn;
    if (j < 256) {
        C256[(size_t)node * 256 + j] = cn;
        short hi = bf_hi(hn);
        Hsplit[(size_t)node * 512 + j] = hi;
        Hsplit[(size_t)node * 512 + 256 + j] = bf_hi(hn - bf_f(hi));
    }
}

extern "C" void kernel_launch(void* const* d_in, const int* in_sizes, int n_in,
                              void* d_out, int out_size, void* d_ws, size_t ws_size,
                              hipStream_t stream) {
    const int* types = (const int*)d_in[0];
    const int* a_idx = (const int*)d_in[1];
    const int* b_idx = (const int*)d_in[2];
    const float* emb = (const float*)d_in[3];
    const float* W_ih = (const float*)d_in[4];
    const float* W_hh = (const float*)d_in[5];
    const float* b_ih = (const float*)d_in[6];
    const float* b_hh = (const float*)d_in[7];
    float* out = (float*)d_out;

    float* ws = (float*)d_ws;
    float* proj = ws;                               // 65536 floats (256 KB)
    float* C256 = ws + 65536;                       // 8388352 floats (32 MB)
    short* Hsplit = (short*)(C256 + 8388352);       // 32767*512 shorts (32 MB)
    short* Whi = Hsplit + 16777216;                 // 2048*512 shorts (2 MB)
    short* Wlo = Whi + 1048576;                     // 2 MB
    float* part = (float*)(Wlo + 1048576);          // 8*16*2048 floats (1 MB)
    // total ws use ~69.3 MB

    proj_kernel<<<256, 256, 0, stream>>>(emb, W_ih, b_ih, b_hh, proj);
    wpack_kernel<<<512, 256, 0, stream>>>(W_hh, Whi, Wlo);
    leaf_kernel<<<32768, 256, 0, stream>>>(types, proj, out, C256, Hsplit);

    for (int d = 13; d >= 0; --d) {
        int base = (1 << d) - 1;
        int B = 1 << d;
        if (B >= 32) {
            int bx = B / 32;
            int J = 2;
            while (bx * J < 512 && J < 16) J <<= 1;
            gemm_lstm_kernel<<<dim3(bx, J), 256, 0, stream>>>(
                a_idx, b_idx, types, out, Whi, Wlo, proj, C256, Hsplit, base, 512 / J);
        } else {
            small_gemm_kernel<<<dim3(B, 8, 8), 256, 0, stream>>>(
                a_idx, b_idx, out, W_hh, part, base);
            small_combine_kernel<<<B * 2, 256, 0, stream>>>(
                a_idx, b_idx, types, part, proj, C256, Hsplit, out, base, B);
        }
    }
}